// Round 9
// baseline (3138.806 us; speedup 1.0000x reference)
//
#include <hip/hip_runtime.h>
#include <cstdint>

// FPS: B=8, N=131072, NPOINT=1024.  Exact-index replication of the jax reference.
//
// v9: v0's proven traffic shape EXACTLY (16 blocks/batch, 16 key-only posts
// per round into 2 cache lines, coalesced poll sweeps of those same 2 lines,
// one barrier/round, monotone tags, parity dbuf, 4 KiB workspace) -- R2-R8
// proved the MALL punishes any deviation in posts/lines/words.  Three LOCAL
// trims that leave the shape untouched:
//   1) LDS-CELL FAN-IN: each wave's lane 63 ds_writes its wave winner to
//      cells[wave]; after the barrier wave0's lanes 0-15 read the 16 cells,
//      group16-DPP-max, lane 0 posts.  Replaces 16 SERIALIZED ds_atomic_max
//      on one address (~300-500cy -> ~150cy).  Race-free by causality, not
//      timing: wave W's round-(t+1) cell write follows W's round-t detect,
//      which follows this block's round-t post, which follows wave0's
//      round-t cell read.  (Same chain covers wave0 itself.)
//   2) 2-DEEP POLL: all 64 lanes load slot[lane&15] (the SAME 2 lines as
//      v0 -- no new lines, no new posts) keeping 2 loads in flight, so the
//      slot is sampled every ~RT/2 instead of every RT.  Expected detect
//      1.5xRT -> 1.25xRT.  Compiler's vmcnt(1) rotation gives the pipeline.
//   3) PACKED-PAIR COMPUTE (proven bit-exact in R4/R5): f32x2 v_pk ops,
//      IEEE-RN identical, fp contract(off) preserves jnp rounding order.
// Packed key u64: [t:15][fp32 dist bits:32][(~idx)&0x1FFFF:17] -> unsigned max
// == (round, dist desc, idx asc) == np.argmax first-max tie-break.  Poisoned
// workspace (0x5555...) has tag 0x2AAA > 1023: never matches a live round.

constexpr int kB = 8;
constexpr int kN = 131072;
constexpr int kNpoint = 1024;
constexpr int kBlocksPerBatch = 16;
constexpr int kThreads = 1024;
constexpr int kWaves = kThreads / 64;          // 16
constexpr int kPPT = 8;
constexpr int kPtsPerBlock = kThreads * kPPT;  // 8192

typedef float f32x2 __attribute__((ext_vector_type(2)));

__device__ __forceinline__ uint64_t u64max(uint64_t a, uint64_t b) {
    return a > b ? a : b;
}

// DPP move of a u64 (both halves, same ctrl); invalid source lanes yield 0,
// the identity for our non-negative packed keys.
template <int CTRL>
__device__ __forceinline__ uint64_t dpp_u64(uint64_t v) {
    int lo = __builtin_amdgcn_update_dpp(0, (int)(uint32_t)v, CTRL, 0xF, 0xF, false);
    int hi = __builtin_amdgcn_update_dpp(0, (int)(uint32_t)(v >> 32), CTRL, 0xF, 0xF, false);
    return ((uint64_t)(uint32_t)hi << 32) | (uint32_t)lo;
}

// Full-wave max; result valid in lane 63 (row_shr/row_bcast ladder).
__device__ __forceinline__ uint64_t wave_max_to_lane63(uint64_t v) {
    v = u64max(v, dpp_u64<0x111>(v));  // row_shr:1
    v = u64max(v, dpp_u64<0x112>(v));  // row_shr:2
    v = u64max(v, dpp_u64<0x114>(v));  // row_shr:4
    v = u64max(v, dpp_u64<0x118>(v));  // row_shr:8
    v = u64max(v, dpp_u64<0x142>(v));  // row_bcast:15
    v = u64max(v, dpp_u64<0x143>(v));  // row_bcast:31
    return v;
}

// Max over each aligned group of 16 lanes (butterfly xor1,2,4,8).
__device__ __forceinline__ uint64_t group16_max(uint64_t v) {
    v = u64max(v, dpp_u64<0xB1>(v));   // quad_perm xor1
    v = u64max(v, dpp_u64<0x4E>(v));   // quad_perm xor2
    v = u64max(v, dpp_u64<0x141>(v));  // row_half_mirror
    v = u64max(v, dpp_u64<0x140>(v));  // row_mirror
    return v;
}

__device__ __forceinline__ uint64_t ld_u64_agent(const uint64_t* p) {
    return __hip_atomic_load(p, __ATOMIC_RELAXED, __HIP_MEMORY_SCOPE_AGENT);
}
__device__ __forceinline__ void st_u64_agent(uint64_t* p, uint64_t v) {
    __hip_atomic_store(p, v, __ATOMIC_RELAXED, __HIP_MEMORY_SCOPE_AGENT);
}

__global__ __launch_bounds__(kThreads, 4) void fps_kernel(
        const float* __restrict__ xyz, float* __restrict__ out,
        uint64_t* __restrict__ slots) {
#pragma clang fp contract(off)
    const int b    = blockIdx.x & 7;    // batch
    const int blk  = blockIdx.x >> 3;   // block within batch, 0..15
    const int tid  = threadIdx.x;
    const int lane = tid & 63;
    const int wave = tid >> 6;          // 0..15

    const float* __restrict__ base = xyz + (size_t)b * kN * 3;

    // Register-resident state as packed pairs: .x is point j=2q, .y is j=2q+1
    // (ascending index order preserved for the first-max tie-break).
    f32x2 X[4], Y[4], Z[4], MD[4];
#pragma unroll
    for (int q = 0; q < 4; ++q) {
        const int p0 = blk * kPtsPerBlock + (2 * q) * kThreads + tid;
        const int p1 = p0 + kThreads;
        X[q].x = base[3 * p0 + 0]; X[q].y = base[3 * p1 + 0];
        Y[q].x = base[3 * p0 + 1]; Y[q].y = base[3 * p1 + 1];
        Z[q].x = base[3 * p0 + 2]; Z[q].y = base[3 * p1 + 2];
        MD[q].x = __builtin_inff(); MD[q].y = __builtin_inff();
    }

    __shared__ uint64_t cells[kWaves];  // per-wave winners; no init needed
                                        // (all 16 written before every barrier)

    // First sample is always point 0.
    float cx = base[0], cy = base[1], cz = base[2];
    if (blk == 0 && tid == 0) {
        float* o = out + (size_t)b * kNpoint * 3;
        o[0] = cx; o[1] = cy; o[2] = cz;
    }

    for (int t = 1; t < kNpoint; ++t) {
        // --- mindist update + per-thread argmax (exact fp32, no contraction) ---
        const f32x2 vcx = {cx, cx}, vcy = {cy, cy}, vcz = {cz, cz};
        float bm = -1.0f;
        int   bj = 0;
#pragma unroll
        for (int q = 0; q < 4; ++q) {
            const f32x2 dx = X[q] - vcx;
            const f32x2 dy = Y[q] - vcy;
            const f32x2 dz = Z[q] - vcz;
            const f32x2 d  = (dx * dx + dy * dy) + dz * dz;  // (xx+yy)+zz, RN
            f32x2 m;
            m.x = fminf(MD[q].x, d.x);
            m.y = fminf(MD[q].y, d.y);
            MD[q] = m;
            // .x is the smaller index -- evaluate first; strict > keeps first max
            const bool g0 = m.x > bm;  bj = g0 ? (2 * q)     : bj;  bm = g0 ? m.x : bm;
            const bool g1 = m.y > bm;  bj = g1 ? (2 * q + 1) : bj;  bm = g1 ? m.y : bm;
        }
        const uint32_t p = (uint32_t)(blk * kPtsPerBlock + bj * kThreads + tid);
        uint64_t pk = ((uint64_t)t << 49) |
                      ((uint64_t)__float_as_uint(bm) << 17) |
                      ((~p) & 0x1FFFFu);

        // --- wave max -> cells[wave] (parallel ds_write, no atomics) ---
        pk = wave_max_to_lane63(pk);
        if (lane == 63) cells[wave] = pk;
        __syncthreads();  // the one barrier: all 16 wave winners in LDS

        uint64_t* const slotbuf = slots + ((size_t)(t & 1) * kB + b) * kBlocksPerBatch;

        // --- wave 0: reduce cells, lane 0 posts (one store, v0 shape) ---
        if (wave == 0) {
            const uint64_t k = (lane < kWaves) ? cells[lane] : 0;
            const uint64_t g = group16_max(k);  // lanes 0-15 all hold block max
            if (lane == 0) st_u64_agent(&slotbuf[blk], g);  // already tagged t
        }

        // --- every wave: 2-deep poll of the 16 slots (same 2 lines as v0) ---
        const uint64_t tt = (uint64_t)t;
        const uint64_t* const sp = &slotbuf[lane & 15];
        uint64_t got;
        {
            uint64_t a = ld_u64_agent(sp);
            for (;;) {
                const uint64_t bb = ld_u64_agent(sp);
                if (__all((a >> 49) == tt)) { got = a; break; }
                a = ld_u64_agent(sp);
                if (__all((bb >> 49) == tt)) { got = bb; break; }
            }
        }
        got = group16_max(got);  // every 16-lane group holds the batch winner

        // broadcast via scalar regs; winner coords from read-only xyz (cached)
        const uint32_t lo = (uint32_t)got;
        const uint32_t widx = 131071u - (__builtin_amdgcn_readfirstlane((int)lo) & 0x1FFFFu);
        cx = base[3 * (size_t)widx + 0];
        cy = base[3 * (size_t)widx + 1];
        cz = base[3 * (size_t)widx + 2];
        if (blk == 0 && tid == 0) {
            float* o = out + ((size_t)b * kNpoint + t) * 3;
            o[0] = cx; o[1] = cy; o[2] = cz;
        }
    }
}

extern "C" void kernel_launch(void* const* d_in, const int* in_sizes, int n_in,
                              void* d_out, int out_size, void* d_ws, size_t ws_size,
                              hipStream_t stream) {
    const float* xyz = (const float*)d_in[0];
    float* out = (float*)d_out;
    uint64_t* slots = (uint64_t*)d_ws;  // 2 * 8 * 16 u64 = 2 KiB used
    fps_kernel<<<dim3(kB * kBlocksPerBatch), dim3(kThreads), 0, stream>>>(xyz, out, slots);
}